// Round 8
// baseline (151.048 us; speedup 1.0000x reference)
//
#include <hip/hip_runtime.h>

#define EPSF 1e-5f

typedef int    int4v   __attribute__((ext_vector_type(4)));
typedef float  float4v __attribute__((ext_vector_type(4)));

// ---------- ws layout (weights/constants only; intermediates live in LDS) ----------
#define W1P_OFF  0
#define W3P_OFF  55296
#define W2D_OFF  110592
#define S1B1_OFF 202752
#define S2B2_OFF 207360
#define S3B3_OFF 211968

// LDS strides (bytes).
// h1 nibble-packed, rows of 30 positions (zero halo cols): 576ch -> 288B +4 pad = 292
//   (73 w === 9 mod 32, coprime: 16-lane gathers hit 16 distinct banks, 2-way = free)
// h2 int8: 576B + 24 pad = 600 (150 w === 22 mod 32: b32/b64 patterns spread evenly)
#define H1S 292
#define H2S 600

__device__ __forceinline__ float lsq_q(float v, float a) {
    float t = v / a;                       // real division (weight alphas not pow2)
    t = fminf(fmaxf(t, -8.0f), 7.0f);
    return rintf(t);                       // RNE == jnp.round
}

__device__ __forceinline__ long q8pack_w(const float* w, int base, float a) {
    unsigned long long v = 0;
    #pragma unroll
    for (int j = 0; j < 8; ++j) {
        int q = (int)lsq_q(w[base + j], a);
        v |= (unsigned long long)(q & 255) << (8 * j);
    }
    return (long)v;
}

// ---------------- prep: quantize/pack weights + fused epilogue constants ----------------
// i8 MFMA 16x16x32 fragment layout (HW-verified r2-r7): lane l holds 8 k-bytes
// k = (l>>4)*8 + j at m/n = l&15;  D: col = l&15, row = (l>>4)*4 + reg.
__global__ __launch_bounds__(256)
void prep_w(const float* __restrict__ w1, const float* __restrict__ w2,
            const float* __restrict__ w3,
            const float* aw1, const float* ax1, const float* ax2,
            const float* aw2, const float* ax3, const float* aw3,
            const float* __restrict__ g1, const float* __restrict__ b1,
            const float* __restrict__ m1, const float* __restrict__ v1,
            const float* __restrict__ g2, const float* __restrict__ b2,
            const float* __restrict__ m2, const float* __restrict__ v2,
            const float* __restrict__ g3, const float* __restrict__ b3,
            const float* __restrict__ m3, const float* __restrict__ v3,
            long* __restrict__ w1p, long* __restrict__ w3p,
            long* __restrict__ w2d,
            float* __restrict__ s1b1, float* __restrict__ s2b2,
            float* __restrict__ s3b3) {
    int id = blockIdx.x * 256 + threadIdx.x;
    if (id < 6912) {                        // w1p: ct 0..35, kc 0..2
        int l = id & 63, t = id >> 6;
        int kc = t % 3, ct = t / 3;
        int co = ct * 16 + (l & 15);
        int ci0 = kc * 32 + (l >> 4) * 8;
        w1p[id] = q8pack_w(w1, co * 96 + ci0, aw1[0]);
    } else if (id < 13824) {                // w3p: ct 0..5, kc 0..17
        int i = id - 6912;
        int l = i & 63, t = i >> 6;
        int kc = t % 18, ct = t / 18;
        int co = ct * 16 + (l & 15);
        int ci0 = kc * 32 + (l >> 4) * 8;
        w3p[i] = q8pack_w(w3, co * 576 + ci0, aw3[0]);
    } else if (id < 25344) {                // w2d: (ct*5 + kc)*64 + l
        int i = id - 13824;
        int l = i & 63, t = i >> 6;
        int kc = t % 5, ct = t / 5;
        int quad = l >> 4, m = l & 15;
        int tap = kc * 2 + (quad >> 1);
        unsigned long long v = 0;
        if (tap <= 8) {
            int mh = m - (quad & 1) * 8;    // lane's channel within this quad's octet?
            if (mh >= 0 && mh < 8) {
                // byte j whose k-channel c' = (quad&1)*8 + 2*(j&3) + (j>>2) equals m
                int j = (mh >> 1) | ((mh & 1) << 2);
                int q = (int)lsq_q(w2[(ct * 16 + m) * 9 + tap], aw2[0]);
                v = (unsigned long long)(unsigned)(q & 255) << (8 * j);
            }
        }
        w2d[i] = (long)v;
    } else if (id < 25920) {                // conv1 fused constants
        int c = id - 25344;
        float s = g1[c] / sqrtf(v1[c] + EPSF);
        float A = aw1[0] * ax1[0];
        float inv = 1.0f / ax2[0];          // exact (alpha = pow2)
        s1b1[c] = A * s * inv;
        s1b1[576 + c] = (b1[c] - m1[c] * s) * inv;
    } else if (id < 26496) {                // dw fused constants
        int c = id - 25920;
        float s = g2[c] / sqrtf(v2[c] + EPSF);
        float A = ax2[0] * aw2[0];
        float inv = 1.0f / ax3[0];
        s2b2[c] = A * s * inv;
        s2b2[576 + c] = (b2[c] - m2[c] * s) * inv;
    } else if (id < 26592) {                // conv3 fused constants
        int c = id - 26496;
        float s = g3[c] / sqrtf(v3[c] + EPSF);
        float A = ax3[0] * aw3[0];
        s3b3[c] = A * s;
        s3b3[96 + c] = b3[c] - m3[c] * s;
    }
}

// ---------------- fused conv1 -> dw(MFMA) -> conv3, block = (batch, 2-row strip) ----
// 2 barriers.  Phase B/C pair-interleaved with split accumulator chains for ILP.
__global__ __launch_bounds__(448, 4)
void fused_k(const float* __restrict__ x, const long* __restrict__ w1p,
             const long* __restrict__ w2d, const long* __restrict__ w3p,
             const float* __restrict__ ax1,
             const float* __restrict__ s1b1, const float* __restrict__ s2b2,
             const float* __restrict__ s3b3, float* __restrict__ out) {
    __shared__ signed char h1[120 * H1S];   // 4 rows x 30 cols, nibble-packed (34.2 KB)
    __shared__ __align__(16) signed char h2[64 * H2S];    // 56 pos + pad, int8 (37.5 KB)
    const int tid = threadIdx.x;
    const int w = tid >> 6, l = tid & 63;
    const int quad = l >> 4, c16 = l & 15;
    const int qh = quad >> 1, ql = quad & 1;
    const int b = blockIdx.x;          // batch 0..31
    const int r0 = blockIdx.y * 2;     // first output row of strip

    // ---- Phase A: conv1 (i8 MFMA, A=weights B=acts) -> h1 nibbles ----
    {
        const int lp = w * 16 + c16;                 // 0..111: row 0..3, col 0..27
        const int row = lp / 28, col = lp - (lp / 28) * 28;
        const int img_row = r0 - 1 + row;
        const bool valid = (unsigned)img_row < 28u;
        const int p = min(max(img_row, 0), 27) * 28 + col;
        const float inv1 = 1.0f / ax1[0];            // exact for pow2 alpha

        long bfr[3];
        #pragma unroll
        for (int kc = 0; kc < 3; ++kc) {             // quantize 8 input ch per quad
            const float* xs = x + (b * 96 + kc * 32 + quad * 8) * 784 + p;
            unsigned long long v = 0;
            #pragma unroll
            for (int j = 0; j < 8; ++j) {
                float t = xs[j * 784] * inv1;
                t = fminf(fmaxf(t, -8.0f), 7.0f);
                int q = (int)rintf(t);
                v |= (unsigned long long)(q & 255) << (8 * j);
            }
            bfr[kc] = (long)v;
        }
        const int pos_h = row * 30 + col + 1;        // halo-extended index
        #pragma unroll 4
        for (int ct = 0; ct < 36; ++ct) {
            int4v acc; acc[0] = 0; acc[1] = 0; acc[2] = 0; acc[3] = 0;
            #pragma unroll
            for (int kc = 0; kc < 3; ++kc)
                acc = __builtin_amdgcn_mfma_i32_16x16x32_i8(
                    w1p[(ct * 3 + kc) * 64 + l], bfr[kc], acc, 0, 0, 0);
            const int co0 = ct * 16 + quad * 4;      // 4 consecutive co per lane
            float4v S = *(const float4v*)(s1b1 + co0);
            float4v B = *(const float4v*)(s1b1 + 576 + co0);
            int pk = 0;
            #pragma unroll
            for (int r = 0; r < 4; ++r) {
                float t = fmaf((float)acc[r], S[r], B[r]);
                t = fminf(fmaxf(t, 0.0f), 7.0f);     // ReLU6 + quant-clip fused
                pk |= ((int)rintf(t)) << (4 * r);    // nibble pack (values 0..7)
            }
            pk = valid ? pk : 0;                     // halo rows: store zeros (no memset)
            *(unsigned short*)(h1 + pos_h * H1S + (co0 >> 1)) = (unsigned short)pk;
        }
    }
    // zero halo COLUMNS (cols 0 and 29 of the 4 rows): 8 pos x 72 words = 576 tasks
    for (int i = tid; i < 576; i += 448) {
        const int q = i / 72, word = i - q * 72;
        const int pos_h = (q >> 1) * 30 + (q & 1) * 29;
        *(int*)(h1 + pos_h * H1S + word * 4) = 0;
    }
    __syncthreads();

    // ---- Phase B: 3x3 depthwise as block-diagonal i8 MFMA, pair-interleaved ----
    int boff[5];                                     // per-lane tap offsets (hoisted)
    #pragma unroll
    for (int kc = 0; kc < 5; ++kc) {
        int tap = kc * 2 + qh;
        tap = min(tap, 8);                           // tap 9 has zero weight in w2d
        const int dh = tap / 3 - 1, dc = tap - (tap / 3) * 3 - 1;
        boff[kc] = (dh * 30 + dc) * H1S;
    }
    for (int t = w; t < 144; t += 14) {              // two tasks per iteration (ILP)
        const int t2r = t + 7;
        const int t2 = (t2r < 144) ? t2r : t;        // tail: duplicate (benign)
        const int ptA = t / 36,  ctA = t - ptA * 36;
        const int ptB = t2 / 36, ctB = t2 - ptB * 36;
        const int posA = ptA * 16 + c16, posB = ptB * 16 + c16;
        const int colA = min(posA, 55) % 28 + (min(posA, 55) / 28) * 0;  // col within row handled below
        // recompute row/col properly
        const int pA = min(posA, 55), pB = min(posB, 55);
        const int rA = pA / 28, cA = pA - rA * 28;
        const int rB = pB / 28, cB = pB - rB * 28;
        (void)colA;
        const signed char* baseA = h1 + ((rA + 1) * 30 + cA + 1) * H1S + ctA * 8 + ql * 4;
        const signed char* baseB = h1 + ((rB + 1) * 30 + cB + 1) * H1S + ctB * 8 + ql * 4;
        int4v a0; a0[0] = 0; a0[1] = 0; a0[2] = 0; a0[3] = 0;
        int4v a1 = a0, b0 = a0, b1 = a0;
        #pragma unroll
        for (int kc = 0; kc < 5; ++kc) {             // split chains: kc<3 and kc>=3
            const unsigned vA = *(const unsigned*)(baseA + boff[kc]);
            const unsigned vB = *(const unsigned*)(baseB + boff[kc]);
            const long bfA = (long)((((unsigned long long)((vA >> 4) & 0x0F0F0F0Fu)) << 32)
                                    | (vA & 0x0F0F0F0Fu));
            const long bfB = (long)((((unsigned long long)((vB >> 4) & 0x0F0F0F0Fu)) << 32)
                                    | (vB & 0x0F0F0F0Fu));
            const long wA = w2d[(ctA * 5 + kc) * 64 + l];
            const long wB = w2d[(ctB * 5 + kc) * 64 + l];
            if (kc < 3) {
                a0 = __builtin_amdgcn_mfma_i32_16x16x32_i8(wA, bfA, a0, 0, 0, 0);
                b0 = __builtin_amdgcn_mfma_i32_16x16x32_i8(wB, bfB, b0, 0, 0, 0);
            } else {
                a1 = __builtin_amdgcn_mfma_i32_16x16x32_i8(wA, bfA, a1, 0, 0, 0);
                b1 = __builtin_amdgcn_mfma_i32_16x16x32_i8(wB, bfB, b1, 0, 0, 0);
            }
        }
        #pragma unroll
        for (int rr = 0; rr < 4; ++rr) { a0[rr] += a1[rr]; b0[rr] += b1[rr]; }
        // epilogue A
        {
            const int c0 = ctA * 16 + quad * 4;
            float4v S = *(const float4v*)(s2b2 + c0);
            float4v B = *(const float4v*)(s2b2 + 576 + c0);
            int pk = 0;
            #pragma unroll
            for (int rr = 0; rr < 4; ++rr) {
                float tt = fmaf((float)a0[rr], S[rr], B[rr]);
                tt = fminf(fmaxf(tt, 0.0f), 7.0f);
                pk |= ((int)rintf(tt)) << (8 * rr);
            }
            if (posA < 56) *(int*)(h2 + posA * H2S + c0) = pk;
        }
        // epilogue B
        {
            const int c0 = ctB * 16 + quad * 4;
            float4v S = *(const float4v*)(s2b2 + c0);
            float4v B = *(const float4v*)(s2b2 + 576 + c0);
            int pk = 0;
            #pragma unroll
            for (int rr = 0; rr < 4; ++rr) {
                float tt = fmaf((float)b0[rr], S[rr], B[rr]);
                tt = fminf(fmaxf(tt, 0.0f), 7.0f);
                pk |= ((int)rintf(tt)) << (8 * rr);
            }
            if (posB < 56 && t2r < 144) *(int*)(h2 + posB * H2S + c0) = pk;
        }
    }
    __syncthreads();

    // ---- Phase C: conv3 (i8 MFMA, A=h2 B=weights) + BN + residual, pair-interleaved ----
    for (int t = w; t < 24; t += 14) {
        const int t2r = t + 7;
        const int t2 = (t2r < 24) ? t2r : t;
        const int ntA = t / 6,  ctA = t - ntA * 6;
        const int ntB = t2 / 6, ctB = t2 - ntB * 6;
        const signed char* arowA = h2 + (ntA * 16 + c16) * H2S + quad * 8;
        const signed char* arowB = h2 + (ntB * 16 + c16) * H2S + quad * 8;
        int4v a0; a0[0] = 0; a0[1] = 0; a0[2] = 0; a0[3] = 0;
        int4v a1 = a0, b0 = a0, b1 = a0;
        #pragma unroll 6
        for (int kc = 0; kc < 18; ++kc) {            // split chains: kc<9 and kc>=9
            const long xA = *(const long*)(arowA + kc * 32);
            const long xB = *(const long*)(arowB + kc * 32);
            const long wA = w3p[(ctA * 18 + kc) * 64 + l];
            const long wB = w3p[(ctB * 18 + kc) * 64 + l];
            if (kc < 9) {
                a0 = __builtin_amdgcn_mfma_i32_16x16x32_i8(xA, wA, a0, 0, 0, 0);
                b0 = __builtin_amdgcn_mfma_i32_16x16x32_i8(xB, wB, b0, 0, 0, 0);
            } else {
                a1 = __builtin_amdgcn_mfma_i32_16x16x32_i8(xA, wA, a1, 0, 0, 0);
                b1 = __builtin_amdgcn_mfma_i32_16x16x32_i8(xB, wB, b1, 0, 0, 0);
            }
        }
        #pragma unroll
        for (int rr = 0; rr < 4; ++rr) { a0[rr] += a1[rr]; b0[rr] += b1[rr]; }
        // epilogue A
        {
            const int nloc = ntA * 16 + quad * 4;
            if (nloc < 56) {
                const int co = ctA * 16 + c16;
                const float S = s3b3[co], Bv = s3b3[96 + co];
                const int off = (b * 96 + co) * 784 + r0 * 28 + nloc;
                const float4v xr = *(const float4v*)(x + off);
                float4v o;
                #pragma unroll
                for (int rr = 0; rr < 4; ++rr)
                    o[rr] = fmaf((float)a0[rr], S, Bv) + xr[rr];
                *(float4v*)(out + off) = o;
            }
        }
        // epilogue B
        if (t2r < 24) {
            const int nloc = ntB * 16 + quad * 4;
            if (nloc < 56) {
                const int co = ctB * 16 + c16;
                const float S = s3b3[co], Bv = s3b3[96 + co];
                const int off = (b * 96 + co) * 784 + r0 * 28 + nloc;
                const float4v xr = *(const float4v*)(x + off);
                float4v o;
                #pragma unroll
                for (int rr = 0; rr < 4; ++rr)
                    o[rr] = fmaf((float)b0[rr], S, Bv) + xr[rr];
                *(float4v*)(out + off) = o;
            }
        }
    }
}

extern "C" void kernel_launch(void* const* d_in, const int* in_sizes, int n_in,
                              void* d_out, int out_size, void* d_ws, size_t ws_size,
                              hipStream_t stream) {
    const float* x   = (const float*)d_in[0];
    const float* w1  = (const float*)d_in[1];
    const float* w2  = (const float*)d_in[2];
    const float* w3  = (const float*)d_in[3];
    const float* aw1 = (const float*)d_in[4];
    const float* ax1 = (const float*)d_in[5];
    const float* g1  = (const float*)d_in[6];
    const float* b1  = (const float*)d_in[7];
    const float* m1  = (const float*)d_in[8];
    const float* v1  = (const float*)d_in[9];
    const float* aw2 = (const float*)d_in[10];
    const float* ax2 = (const float*)d_in[11];
    const float* g2  = (const float*)d_in[12];
    const float* b2  = (const float*)d_in[13];
    const float* m2  = (const float*)d_in[14];
    const float* v2  = (const float*)d_in[15];
    const float* aw3 = (const float*)d_in[16];
    const float* ax3 = (const float*)d_in[17];
    const float* g3  = (const float*)d_in[18];
    const float* b3  = (const float*)d_in[19];
    const float* m3  = (const float*)d_in[20];
    const float* v3  = (const float*)d_in[21];

    char* ws = (char*)d_ws;
    long* w1p = (long*)(ws + W1P_OFF);
    long* w3p = (long*)(ws + W3P_OFF);
    long* w2d = (long*)(ws + W2D_OFF);
    float* s1b1 = (float*)(ws + S1B1_OFF);
    float* s2b2 = (float*)(ws + S2B2_OFF);
    float* s3b3 = (float*)(ws + S3B3_OFF);

    float* out = (float*)d_out;

    prep_w<<<104, 256, 0, stream>>>(w1, w2, w3, aw1, ax1, ax2, aw2, ax3, aw3,
                                    g1, b1, m1, v1, g2, b2, m2, v2, g3, b3, m3, v3,
                                    w1p, w3p, w2d, s1b1, s2b2, s3b3);
    dim3 grid(32, 14);
    fused_k<<<grid, 448, 0, stream>>>(x, w1p, w2d, w3p, ax1, s1b1, s2b2, s3b3, out);
}